// Round 13
// baseline (35.472 us; speedup 1.0000x reference)
//
#include <hip/hip_runtime.h>

constexpr int N_NODES  = 4000000;
constexpr int N_GRAPHS = 4096;
constexpr int D_FEAT   = 8;
constexpr int N_CLS    = 10;
constexpr int CHUNK    = 512;                             // nodes per wave
constexpr int NCH      = (N_NODES + CHUNK - 1) / CHUNK;   // 7813 chunks
constexpr int ACC_F32  = N_GRAPHS * D_FEAT + N_GRAPHS;    // sums + cnts floats

typedef float f32x4 __attribute__((ext_vector_type(4)));
typedef int   i32x4 __attribute__((ext_vector_type(4)));

// ws layout: [ sums 4096*8 f32 | cnts 4096 f32 ]

// Pool: wave w owns nodes [w*512, w*512+512). It reads its own 512 ids
// (8/lane, in-register), finds segment transitions via ballot, accumulates
// each span with unit-stride float4 loads, flushes one atomic set per span.
// No bounds array, no search, no extra pass over ids.
__global__ __launch_bounds__(256) void pool_seg(
    const f32x4* __restrict__ xf,      // [N_NODES*2] flat float4 view of x
    const i32x4* __restrict__ ids4,    // [N_NODES/4]
    const int*   __restrict__ ids,     // scalar view (tail broadcast only)
    float*       __restrict__ sums,    // [N_GRAPHS*8]
    float*       __restrict__ cnts)    // [N_GRAPHS]
{
    int w = blockIdx.x * 4 + (threadIdx.x >> 6);
    if (w >= NCH) return;
    int lane = threadIdx.x & 63;
    int c0 = w * CHUNK;
    int c1 = min(c0 + CHUNK, N_NODES);

    // This lane's 8 ids (positions base..base+7). Tail chunk: OOB lanes are
    // fully OOB (256%8==0); clamp them to ids[N-1] -> no spurious transitions.
    int base = c0 + lane * 8;
    i32x4 v0, v1;
    if (base + 8 <= N_NODES) {
        v0 = ids4[base >> 2];
        v1 = ids4[(base >> 2) + 1];
    } else {
        int last = ids[N_NODES - 1];
        v0 = (i32x4)(last);
        v1 = (i32x4)(last);
    }
    int gcur = __shfl(v0.x, 0);        // ids[c0]
    int p = c0;

    while (true) {
        // First position q > p with ids[q] != gcur (within this chunk).
        unsigned m8 = 0;
        m8 |= (v0.x != gcur && base + 0 > p) ? 1u   : 0u;
        m8 |= (v0.y != gcur && base + 1 > p) ? 2u   : 0u;
        m8 |= (v0.z != gcur && base + 2 > p) ? 4u   : 0u;
        m8 |= (v0.w != gcur && base + 3 > p) ? 8u   : 0u;
        m8 |= (v1.x != gcur && base + 4 > p) ? 16u  : 0u;
        m8 |= (v1.y != gcur && base + 5 > p) ? 32u  : 0u;
        m8 |= (v1.z != gcur && base + 6 > p) ? 64u  : 0u;
        m8 |= (v1.w != gcur && base + 7 > p) ? 128u : 0u;

        int j0   = __builtin_ctz(m8 | 0x100u);   // 8 when m8==0 (then unused)
        int cpos = base + j0;
        int cid  = j0 < 4 ? (j0 < 2 ? (j0 == 0 ? v0.x : v0.y)
                                    : (j0 == 2 ? v0.z : v0.w))
                          : (j0 < 6 ? (j0 == 4 ? v1.x : v1.y)
                                    : (j0 == 6 ? v1.z : v1.w));
        unsigned long long ball = __ballot(m8 != 0);
        int pend = c1, gnext = 0;
        if (ball != 0ull) {
            int fl = __builtin_ctzll(ball);      // lowest lane with a transition
            pend  = __shfl(cpos, fl);
            gnext = __shfl(cid,  fl);
        }

        // Accumulate span [p, pend): unit-stride f4, lane parity = feat half.
        f32x4 a0 = (f32x4)(0.f), a1 = (f32x4)(0.f),
              a2 = (f32x4)(0.f), a3 = (f32x4)(0.f);
        int i    = 2 * p + lane;
        int endf = 2 * pend;
        int full = (endf - 2 * p) >> 8;          // unpredicated 256-f4 rounds
        for (int it = 0; it < full; ++it, i += 256) {
            a0 += xf[i];
            a1 += xf[i +  64];
            a2 += xf[i + 128];
            a3 += xf[i + 192];
        }
        for (; i < endf; i += 64) a0 += xf[i];   // exec-masked tail
        f32x4 acc = (a0 + a1) + (a2 + a3);

        // Butterfly over even offsets: even lanes sum feats 0-3, odd 4-7.
        #pragma unroll
        for (int off = 32; off >= 2; off >>= 1) {
            acc.x += __shfl_xor(acc.x, off);
            acc.y += __shfl_xor(acc.y, off);
            acc.z += __shfl_xor(acc.z, off);
            acc.w += __shfl_xor(acc.w, off);
        }
        // lane 0 (even) holds feats 0-3 totals; lane 1 (odd) holds feats 4-7.
        if (lane < 2) {
            float* s = sums + (size_t)gcur * D_FEAT + lane * 4;
            atomicAdd(s + 0, acc.x);
            atomicAdd(s + 1, acc.y);
            atomicAdd(s + 2, acc.z);
            atomicAdd(s + 3, acc.w);
        }
        if (lane == 0)
            atomicAdd(cnts + gcur, (float)(pend - p));

        if (pend >= c1) break;
        p = pend; gcur = gnext;
    }
}

// Finalize: mean + tiny linear epilogue.
__global__ __launch_bounds__(256) void finalize(
    const float* __restrict__ sums, const float* __restrict__ cnts,
    const float* __restrict__ W, const float* __restrict__ bias,
    float* __restrict__ out)
{
    int idx = blockIdx.x * blockDim.x + threadIdx.x;
    if (idx >= N_GRAPHS * N_CLS) return;
    int g = idx / N_CLS;
    int c = idx % N_CLS;
    float inv = 1.0f / cnts[g];
    const float* s = sums + (size_t)g * D_FEAT;
    const float* w = W + (size_t)c * D_FEAT;
    float a = bias[c];
    #pragma unroll
    for (int k = 0; k < D_FEAT; ++k)
        a += (s[k] * inv) * w[k];
    out[idx] = a;
}

extern "C" void kernel_launch(void* const* d_in, const int* in_sizes, int n_in,
                              void* d_out, int out_size, void* d_ws, size_t ws_size,
                              hipStream_t stream) {
    const float* x   = (const float*)d_in[0];   // [4M, 8] f32
    const int*   ids = (const int*)d_in[1];     // [4M] sorted segment ids
    // d_in[2] input_ids, d_in[3] attention_mask: unused by the forward
    const float* W   = (const float*)d_in[4];   // [10, 8]
    const float* b   = (const float*)d_in[5];   // [10]
    float*       out = (float*)d_out;           // [4096, 10]

    float* sums = (float*)d_ws;
    float* cnts = sums + (size_t)N_GRAPHS * D_FEAT;

    hipMemsetAsync(d_ws, 0, (size_t)ACC_F32 * sizeof(float), stream);

    int pool_blocks = (NCH + 3) / 4;            // 1954
    pool_seg<<<pool_blocks, 256, 0, stream>>>(
        (const f32x4*)x, (const i32x4*)ids, ids, sums, cnts);

    finalize<<<(N_GRAPHS * N_CLS + 255) / 256, 256, 0, stream>>>(
        sums, cnts, W, b, out);
}

// Round 14
// 35.033 us; speedup vs baseline: 1.0125x; 1.0125x over previous
//
#include <hip/hip_runtime.h>

constexpr int N_NODES  = 4000000;
constexpr int N_GRAPHS = 4096;
constexpr int D_FEAT   = 8;
constexpr int N_CLS    = 10;
constexpr int CHUNK    = 512;                             // nodes per wave
constexpr int NCH      = (N_NODES + CHUNK - 1) / CHUNK;   // 7813
constexpr int ACC_F32  = N_GRAPHS * D_FEAT + N_GRAPHS;    // sums + cnts floats

typedef float f32x4 __attribute__((ext_vector_type(4)));
typedef int   i32x4 __attribute__((ext_vector_type(4)));

__device__ __forceinline__ int idat(const i32x4& v0, const i32x4& v1, int j) {
    switch (j) {
        case 0: return v0.x; case 1: return v0.y;
        case 2: return v0.z; case 3: return v0.w;
        case 4: return v1.x; case 5: return v1.y;
        case 6: return v1.z; default: return v1.w;
    }
}

// Parity-split wave reduction + atomic flush. After the even-offset butterfly,
// lane 0 holds the even-lane total (feats 0-3), lane 1 the odd-lane total (4-7).
__device__ __forceinline__ void wave_flush(
    f32x4 acc, int lane, int g, float cnt,
    float* __restrict__ sums, float* __restrict__ cnts)
{
    #pragma unroll
    for (int off = 32; off >= 2; off >>= 1) {
        acc.x += __shfl_xor(acc.x, off);
        acc.y += __shfl_xor(acc.y, off);
        acc.z += __shfl_xor(acc.z, off);
        acc.w += __shfl_xor(acc.w, off);
    }
    if (lane < 2) {
        float* s = sums + (size_t)g * D_FEAT + lane * 4;
        atomicAdd(s + 0, acc.x);
        atomicAdd(s + 1, acc.y);
        atomicAdd(s + 2, acc.z);
        atomicAdd(s + 3, acc.w);
    }
    if (lane == 0) atomicAdd(cnts + g, cnt);
}

// Wave w owns nodes [w*512, w*512+512). Reads its own 512 ids (coalesced, the
// only ids bytes it ever touches), resolves the (at most one, by data) internal
// transition BEFORE streaming, then one unbroken ILP-4 float4 stream over the
// whole chunk with a branchless two-way accumulator split. Flushes after.
__global__ __launch_bounds__(256) void pool_seg(
    const f32x4* __restrict__ xf, const float* __restrict__ x,
    const i32x4* __restrict__ ids4, const int* __restrict__ ids,
    float* __restrict__ sums, float* __restrict__ cnts)
{
    int w = blockIdx.x * 4 + (threadIdx.x >> 6);
    if (w >= NCH) return;
    int lane = threadIdx.x & 63;
    int c0 = w * CHUNK;
    int c1 = min(c0 + CHUNK, N_NODES);

    // This lane's 8 ids. Tail chunk: OOB lanes are fully OOB (256 % 8 == 0);
    // clamp to ids[N-1] -> no spurious transitions.
    int base = c0 + lane * 8;
    i32x4 v0, v1;
    if (base + 8 <= N_NODES) {
        v0 = ids4[base >> 2];
        v1 = ids4[(base >> 2) + 1];
    } else {
        i32x4 l = (i32x4)(ids[N_NODES - 1]);
        v0 = l; v1 = l;
    }
    int gcur = __shfl(v0.x, 0);                 // ids[c0]

    // Per-lane transition mask (bit j: ids[base+j] != ids[base+j-1]).
    int pl = __shfl(v1.w, (lane == 0) ? 0 : (lane - 1));
    int pv = (lane == 0) ? v0.x : pl;
    unsigned m8 = 0;
    m8 |= (v0.x != pv)   ? 1u   : 0u;
    m8 |= (v0.y != v0.x) ? 2u   : 0u;
    m8 |= (v0.z != v0.y) ? 4u   : 0u;
    m8 |= (v0.w != v0.z) ? 8u   : 0u;
    m8 |= (v1.x != v0.w) ? 16u  : 0u;
    m8 |= (v1.y != v1.x) ? 32u  : 0u;
    m8 |= (v1.z != v1.y) ? 64u  : 0u;
    m8 |= (v1.w != v1.z) ? 128u : 0u;

    int tot = __popc(m8);
    #pragma unroll
    for (int off = 32; off; off >>= 1) tot += __shfl_xor(tot, off);

    if (tot <= 1) {
        // Resolve the single boundary (if any) BEFORE streaming.
        int bnd = c1, gnext = 0;
        if (tot == 1) {
            int j   = __builtin_ctz(m8 | 0x100u);
            int pos = base + j;
            int idj = idat(v0, v1, j);
            unsigned long long ball = __ballot(m8 != 0);
            int fl = (int)__builtin_ctzll(ball);
            bnd   = __shfl(pos, fl);
            gnext = __shfl(idj, fl);
        }
        int bf = 2 * bnd;                        // boundary in float4 units
        f32x4 z = (f32x4)(0.f);
        f32x4 aA0=z, aA1=z, aA2=z, aA3=z;        // graph gcur
        f32x4 aB0=z, aB1=z, aB2=z, aB3=z;        // graph gnext

        int u    = 2 * c0;                       // iteration base (f4 units)
        int uend = u + 2 * (c1 - c0);            // 1024 (or 512 for tail)
        for (; u < uend; u += 256) {
            int i0 = u + lane;
            f32x4 x0 = xf[i0], x1 = xf[i0+64], x2 = xf[i0+128], x3 = xf[i0+192];
            if (u + 256 <= bf) {                 // whole iter before boundary
                aA0 += x0; aA1 += x1; aA2 += x2; aA3 += x3;
            } else if (u >= bf) {                // whole iter after boundary
                aB0 += x0; aB1 += x1; aB2 += x2; aB3 += x3;
            } else {                             // straddle: branchless split
                aA0 += (i0       < bf) ? x0 : z;  aB0 += (i0       < bf) ? z : x0;
                aA1 += (i0 +  64 < bf) ? x1 : z;  aB1 += (i0 +  64 < bf) ? z : x1;
                aA2 += (i0 + 128 < bf) ? x2 : z;  aB2 += (i0 + 128 < bf) ? z : x2;
                aA3 += (i0 + 192 < bf) ? x3 : z;  aB3 += (i0 + 192 < bf) ? z : x3;
            }
        }
        wave_flush((aA0 + aA1) + (aA2 + aA3), lane, gcur,
                   (float)(bnd - c0), sums, cnts);
        if (bnd < c1)
            wave_flush((aB0 + aB1) + (aB2 + aB3), lane, gnext,
                       (float)(c1 - bnd), sums, cnts);
    } else {
        // General fallback (>=2 transitions in a chunk: graphs < 512 nodes).
        // Correct for any input; never triggers on this data distribution.
        for (int j = 0; j < 8; ++j) {
            int n = base + j;
            if (n < c1) {
                int g = idat(v0, v1, j);
                #pragma unroll
                for (int k = 0; k < D_FEAT; ++k)
                    atomicAdd(&sums[(size_t)g * D_FEAT + k],
                              x[(size_t)n * D_FEAT + k]);
                atomicAdd(&cnts[g], 1.0f);
            }
        }
    }
}

// Finalize: mean + tiny linear epilogue.
__global__ __launch_bounds__(256) void finalize(
    const float* __restrict__ sums, const float* __restrict__ cnts,
    const float* __restrict__ W, const float* __restrict__ bias,
    float* __restrict__ out)
{
    int idx = blockIdx.x * blockDim.x + threadIdx.x;
    if (idx >= N_GRAPHS * N_CLS) return;
    int g = idx / N_CLS;
    int c = idx % N_CLS;
    float inv = 1.0f / cnts[g];
    const float* s = sums + (size_t)g * D_FEAT;
    const float* w = W + (size_t)c * D_FEAT;
    float a = bias[c];
    #pragma unroll
    for (int k = 0; k < D_FEAT; ++k)
        a += (s[k] * inv) * w[k];
    out[idx] = a;
}

extern "C" void kernel_launch(void* const* d_in, const int* in_sizes, int n_in,
                              void* d_out, int out_size, void* d_ws, size_t ws_size,
                              hipStream_t stream) {
    const float* x   = (const float*)d_in[0];   // [4M, 8] f32
    const int*   ids = (const int*)d_in[1];     // [4M] sorted segment ids
    // d_in[2] input_ids, d_in[3] attention_mask: unused by the forward
    const float* W   = (const float*)d_in[4];   // [10, 8]
    const float* b   = (const float*)d_in[5];   // [10]
    float*       out = (float*)d_out;           // [4096, 10]

    float* sums = (float*)d_ws;
    float* cnts = sums + (size_t)N_GRAPHS * D_FEAT;

    hipMemsetAsync(d_ws, 0, (size_t)ACC_F32 * sizeof(float), stream);

    int pool_blocks = (NCH + 3) / 4;            // 1954
    pool_seg<<<pool_blocks, 256, 0, stream>>>(
        (const f32x4*)x, x, (const i32x4*)ids, ids, sums, cnts);

    finalize<<<(N_GRAPHS * N_CLS + 255) / 256, 256, 0, stream>>>(
        sums, cnts, W, b, out);
}

// Round 15
// 32.518 us; speedup vs baseline: 1.0909x; 1.0773x over previous
//
#include <hip/hip_runtime.h>

constexpr int N_NODES  = 4000000;
constexpr int N_GRAPHS = 4096;
constexpr int D_FEAT   = 8;
constexpr int N_CLS    = 10;
constexpr int GPB      = 4;      // graphs per block, one per wave
constexpr int WIN      = 8192;   // half-window for warm-start search (~8 sigma)

typedef float f32x4 __attribute__((ext_vector_type(4)));

// One dispatch, no workspace, no atomics.
// Block b owns graphs [g0, g0+4). It searches ONLY the two endpoints
// bounds[g0], bounds[g0+4] (two cooperative 32-ary lower_bounds), then reads
// ids[s,e) coalesced (the mandatory bytes) to derive the 3 interior bounds
// in LDS. Wave w streams graph g0+w and writes its 10 logits directly.
__global__ __launch_bounds__(256) void fused_all(
    const float* __restrict__ x,       // [N_NODES, 8]
    const int*   __restrict__ ids,     // [N_NODES] sorted
    const float* __restrict__ W,       // [N_CLS, D_FEAT]
    const float* __restrict__ bias,    // [N_CLS]
    float*       __restrict__ out)     // [N_GRAPHS, N_CLS]
{
    const f32x4* xf = (const f32x4*)x; // [N_NODES*2] flat float4 view
    int g0   = blockIdx.x * GPB;
    int wid  = threadIdx.x >> 6;
    int lane = threadIdx.x & 63;
    int half = lane >> 5;              // 0: search g0, 1: search g0+GPB
    int l32  = lane & 31;
    int target = g0 + half * GPB;

    // Warm start around the linear estimate; bracket-check, fallback if bad.
    int est = (int)((long long)target * N_NODES / N_GRAPHS);
    int lo = est - WIN; if (lo < 0) lo = 0;
    int hi = est + WIN; if (hi > N_NODES) hi = N_NODES;
    {
        bool okL = (lo == 0)       || (ids[lo - 1] < target);
        bool okR = (hi == N_NODES) || (ids[hi] >= target);
        if (!(okL && okR)) { lo = 0; hi = N_NODES; }  // ~never; correctness net
    }

    // 32-ary cooperative lower_bound (each 32-lane half searches its target).
    while (hi - lo > 32) {
        int chunk = (hi - lo + 31) >> 5;
        int pos = lo + l32 * chunk;
        int v = (pos < hi) ? ids[pos] : 0x7fffffff;
        unsigned long long m = __ballot(v < target);
        unsigned int mm = half ? (unsigned int)(m >> 32) : (unsigned int)m;
        int cnt = __popc(mm);
        int nlo = cnt ? lo + (cnt - 1) * chunk + 1 : lo;
        int nhi = (cnt < 32) ? min(lo + cnt * chunk, hi) : hi;
        lo = nlo; hi = nhi;
    }
    {   // final round, chunk = 1
        int pos = lo + l32;
        int v = (pos < hi) ? ids[pos] : 0x7fffffff;
        unsigned long long m = __ballot(v < target);
        unsigned int mm = half ? (unsigned int)(m >> 32) : (unsigned int)m;
        lo += __popc(mm);
    }
    int s = __shfl(lo, 0);             // lower_bound(g0)
    int e = __shfl(lo, 32);            // lower_bound(g0+GPB)

    // Interior bounds via coalesced transition scan of ids[s,e).
    __shared__ int lb[GPB + 1];
    if (threadIdx.x < GPB + 1) lb[threadIdx.x] = -1;
    __syncthreads();
    if (threadIdx.x == 0) { lb[0] = s; lb[GPB] = e; }
    for (int i = s + 1 + (int)threadIdx.x; i < e; i += 256) {
        int cur  = ids[i];
        int prev = ids[i - 1];         // previous lane's line: L1 hit
        if (cur != prev) {             // unique writer per slot (ids sorted)
            for (int k = prev + 1; k <= cur; ++k) lb[k - g0] = i;
        }
    }
    __syncthreads();
    if (threadIdx.x == 0) {            // empty-graph fixup (right-to-left)
        for (int k = GPB - 1; k >= 1; --k) if (lb[k] < 0) lb[k] = lb[k + 1];
    }
    __syncthreads();

    int gs = lb[wid];
    int ge = lb[wid + 1];

    // Per-wave unit-stride float4 stream over graph g0+wid.
    // Lane parity fixes its feature half (even: feats 0-3, odd: 4-7).
    f32x4 a0 = (f32x4)(0.f), a1 = (f32x4)(0.f),
          a2 = (f32x4)(0.f), a3 = (f32x4)(0.f);
    int i    = 2 * gs + lane;
    int endf = 2 * ge;
    int full = (endf - 2 * gs) >> 8;   // unpredicated 256-f4 rounds
    for (int it = 0; it < full; ++it, i += 256) {
        a0 += xf[i];
        a1 += xf[i +  64];
        a2 += xf[i + 128];
        a3 += xf[i + 192];
    }
    for (; i < endf; i += 64) a0 += xf[i];   // exec-masked tail
    f32x4 acc = (a0 + a1) + (a2 + a3);

    // Butterfly over even offsets: every even lane ends with the full
    // feats0-3 totals, every odd lane with feats4-7.
    #pragma unroll
    for (int off = 32; off >= 2; off >>= 1) {
        acc.x += __shfl_xor(acc.x, off);
        acc.y += __shfl_xor(acc.y, off);
        acc.z += __shfl_xor(acc.z, off);
        acc.w += __shfl_xor(acc.w, off);
    }
    // Broadcast the 8 sums to all lanes (lane 0 = feats 0-3, lane 1 = 4-7).
    float m0 = __shfl(acc.x, 0), m1 = __shfl(acc.y, 0);
    float m2 = __shfl(acc.z, 0), m3 = __shfl(acc.w, 0);
    float m4 = __shfl(acc.x, 1), m5 = __shfl(acc.y, 1);
    float m6 = __shfl(acc.z, 1), m7 = __shfl(acc.w, 1);

    if (lane < N_CLS) {
        float inv = 1.0f / (float)(ge - gs);
        const float* w = W + (size_t)lane * D_FEAT;
        float a = bias[lane];
        a += (m0 * inv) * w[0] + (m1 * inv) * w[1]
           + (m2 * inv) * w[2] + (m3 * inv) * w[3]
           + (m4 * inv) * w[4] + (m5 * inv) * w[5]
           + (m6 * inv) * w[6] + (m7 * inv) * w[7];
        out[(size_t)(g0 + wid) * N_CLS + lane] = a;
    }
}

extern "C" void kernel_launch(void* const* d_in, const int* in_sizes, int n_in,
                              void* d_out, int out_size, void* d_ws, size_t ws_size,
                              hipStream_t stream) {
    const float* x   = (const float*)d_in[0];   // [4M, 8] f32
    const int*   ids = (const int*)d_in[1];     // [4M] sorted segment ids
    // d_in[2] input_ids, d_in[3] attention_mask: unused by the forward
    const float* W   = (const float*)d_in[4];   // [10, 8]
    const float* b   = (const float*)d_in[5];   // [10]
    float*       out = (float*)d_out;           // [4096, 10]

    fused_all<<<N_GRAPHS / GPB, 256, 0, stream>>>(x, ids, W, b, out);
}